// Round 5
// baseline (3865.919 us; speedup 1.0000x reference)
//
#include <hip/hip_runtime.h>
#include <math.h>

typedef unsigned short u16;
typedef unsigned int   u32;
typedef __attribute__((ext_vector_type(8))) short s8v;   // 8 x bf16 (bit pattern)
typedef __attribute__((ext_vector_type(4))) float f4v;

#define MFMA16(a,b,c) __builtin_amdgcn_mfma_f32_16x16x32_bf16((a),(b),(c),0,0,0)

__device__ __forceinline__ u16 f2bf(float f){
  union { float f; u32 u; } v; v.f = f;
  u32 r = v.u + 0x7fffu + ((v.u >> 16) & 1u);   // RNE
  return (u16)(r >> 16);
}

__device__ __forceinline__ void gload16(const void* g, void* l){
  __builtin_amdgcn_global_load_lds((const __attribute__((address_space(1))) u32*)g,
                                   (__attribute__((address_space(3))) u32*)l, 16, 0, 0);
}

// ---------------- prep: f32->bf16 conversions + rope tables ----------------
__device__ __forceinline__ void cvt8(const float* __restrict__ s, u16* __restrict__ d){
  const float4* s4 = (const float4*)s;
  float4 a = s4[0], b = s4[1];
  uint4 o;
  o.x = (u32)f2bf(a.x) | ((u32)f2bf(a.y) << 16);
  o.y = (u32)f2bf(a.z) | ((u32)f2bf(a.w) << 16);
  o.z = (u32)f2bf(b.x) | ((u32)f2bf(b.y) << 16);
  o.w = (u32)f2bf(b.z) | ((u32)f2bf(b.w) << 16);
  *(uint4*)d = o;
}

__global__ void k_prep(const float* __restrict__ th_in, const float* __restrict__ fcw,
                       const float* __restrict__ kw, const float* __restrict__ vw,
                       const int* __restrict__ pos,
                       u16* __restrict__ th_bf, u16* __restrict__ fcw_bf, u16* __restrict__ kvw_bf,
                       float* __restrict__ cost, float* __restrict__ sint)
{
  long t = (long)blockIdx.x * blockDim.x + threadIdx.x;
  long stride = (long)gridDim.x * blockDim.x;
  for (long i = t; i < 104857600L/8; i += stride) cvt8(th_in + i*8, th_bf + i*8);
  for (long i = t; i < 32768000L/8; i += stride) cvt8(fcw + i*8, fcw_bf + i*8);
  for (long i = t; i < 6553600L/8; i += stride){
    long e = i*8; long l = e / 1310720, j = e - l*1310720;
    cvt8(kw + e, kvw_bf + (2*l)*1310720 + j);
    cvt8(vw + e, kvw_bf + (2*l+1)*1310720 + j);
  }
  for (long i = t; i < 4L*2064*64; i += stride){
    int d = (int)(i & 63); long bs = i >> 6;
    float p = (float)pos[bs];
    float inv = exp2f(-0.3114307589f * (float)d);   // 1e6^(-d/64)
    float a = p * inv;
    cost[i] = cosf(a); sint[i] = sinf(a);
  }
}

// ---------------- big BT GEMM: C[m,n] = sum_k A[m,k]*B[n,k], bf16 in, f32 out
__global__ __launch_bounds__(256) void k_gemm_bt(
    const u16* __restrict__ A, const u16* __restrict__ Bw, float* __restrict__ C,
    int M, int N, int K, long sB, long sC)
{
  __shared__ u16 lA[128*32];
  __shared__ u16 lB[128*32];
  const u16* Bz = Bw + (long)blockIdx.z * sB;
  float* Cz = C + (long)blockIdx.z * sC;
  const int n0 = blockIdx.x*128, m0 = blockIdx.y*128;
  const int tid = threadIdx.x, lane = tid & 63, w = tid >> 6;
  const int srow = (w<<4) + (lane>>2), skc = (lane&3)*8;
  const u16* gA = A + (long)(m0 + srow)*K + skc;
  const u16* gB = Bz + (long)(n0 + srow)*K + skc;
  u16* lAw = lA + w*512; u16* lBw = lB + w*512;
  const int wm = (w>>1)*64, wn = (w&1)*64;
  const int fr = lane & 15, fg = lane >> 4;
  const f4v z4 = {0.f,0.f,0.f,0.f};
  f4v acc[4][4];
  #pragma unroll
  for (int m=0;m<4;m++){
    #pragma unroll
    for (int n=0;n<4;n++) acc[m][n] = z4;
  }
  for (int k0 = 0; k0 < K; k0 += 32){
    gload16(gA + k0, lAw);
    gload16(gA + (long)64*K + k0, lAw + 2048);
    gload16(gB + k0, lBw);
    gload16(gB + (long)64*K + k0, lBw + 2048);
    __syncthreads();
    s8v af[4], bf[4];
    #pragma unroll
    for (int m=0;m<4;m++) af[m] = *(const s8v*)&lA[(wm + m*16 + fr)*32 + fg*8];
    #pragma unroll
    for (int n=0;n<4;n++) bf[n] = *(const s8v*)&lB[(wn + n*16 + fr)*32 + fg*8];
    #pragma unroll
    for (int m=0;m<4;m++){
      #pragma unroll
      for (int n=0;n<4;n++) acc[m][n] = MFMA16(af[m], bf[n], acc[m][n]);
    }
    __syncthreads();
  }
  #pragma unroll
  for (int m=0;m<4;m++){
    int row = m0 + wm + m*16 + fg*4;
    #pragma unroll
    for (int n=0;n<4;n++){
      int col = n0 + wn + n*16 + fr;
      f4v a = acc[m][n];
      #pragma unroll
      for (int r=0;r<4;r++) Cz[(long)(row+r)*N + col] = a[r];
    }
  }
}

// ---------------- skinny GEMM: A(64xK bf16) * W(NxK f32)^T -> atomicAdd C(64xldc f32)
__global__ __launch_bounds__(256) void k_skinny(
    const u16* __restrict__ A, const float* __restrict__ W, float* __restrict__ C,
    int K, int ldc, int coff, int klen)
{
  __shared__ u16 lA[64*64];
  __shared__ u16 lW[64*64];
  const int n0 = blockIdx.x*64;
  const int kb = blockIdx.y*klen;
  const int tid = threadIdx.x, lane = tid&63, w = tid>>6;
  const int fr = lane&15, fg = lane>>4;
  const int ar = (w<<3) + (lane>>3), akc = (lane&7)*8;
  const u16* gA = A + (long)ar*K + kb + akc;
  u16* lAw = lA + w*512;
  const int wr = tid>>4, wc = (tid&15)*4;
  const float* gW0 = W + (long)(n0+wr)*K + kb + wc;
  const f4v z4 = {0.f,0.f,0.f,0.f};
  f4v acc[4];
  #pragma unroll
  for (int m=0;m<4;m++) acc[m]=z4;
  for (int k0=0;k0<klen;k0+=64){
    gload16(gA + k0, lAw);
    gload16(gA + (long)32*K + k0, lAw + 2048);
    #pragma unroll
    for (int p=0;p<4;p++){
      float4 v = *(const float4*)(gW0 + k0 + (long)p*16*K);
      uint2 pk;
      pk.x = (u32)f2bf(v.x) | ((u32)f2bf(v.y)<<16);
      pk.y = (u32)f2bf(v.z) | ((u32)f2bf(v.w)<<16);
      *(uint2*)&lW[(wr + p*16)*64 + wc] = pk;
    }
    __syncthreads();
    #pragma unroll
    for (int ks=0;ks<2;ks++){
      s8v bfr = *(const s8v*)&lW[((w<<4) + fr)*64 + ks*32 + fg*8];
      #pragma unroll
      for (int m=0;m<4;m++){
        s8v afr = *(const s8v*)&lA[(m*16 + fr)*64 + ks*32 + fg*8];
        acc[m] = MFMA16(afr, bfr, acc[m]);
      }
    }
    __syncthreads();
  }
  const int col = coff + n0 + (w<<4) + fr;
  #pragma unroll
  for (int m=0;m<4;m++){
    int row = m*16 + fg*4;
    #pragma unroll
    for (int r=0;r<4;r++) atomicAdd(&C[(long)(row+r)*ldc + col], acc[m][r]);
  }
}

// ---------------- row RMS norm (f32 in, bf16 or f32 out) ----------------
__global__ __launch_bounds__(256) void k_rms_row(
    const float* __restrict__ x, const float* __restrict__ w,
    u16* __restrict__ obf, float* __restrict__ of32, int ncols)
{
  const int row = blockIdx.x, tid = threadIdx.x;
  const float* xr = x + (long)row*ncols;
  float ss = 0.f;
  for (int i = tid; i < ncols; i += 256){ float v = xr[i]; ss = fmaf(v,v,ss); }
  #pragma unroll
  for (int msk=1; msk<64; msk<<=1) ss += __shfl_xor(ss, msk);
  __shared__ float red[4];
  if ((tid&63)==0) red[tid>>6] = ss;
  __syncthreads();
  float tot = red[0]+red[1]+red[2]+red[3];
  float sc = rsqrtf(tot/(float)ncols + 1e-6f);
  if (obf){
    for (int i = tid; i < ncols; i += 256) obf[(long)row*ncols+i] = f2bf(xr[i]*sc*w[i]);
  } else {
    for (int i = tid; i < ncols; i += 256) of32[(long)row*ncols+i] = xr[i]*sc*w[i];
  }
}

// ---------------- context K post: RMS(kn) + RoPE -> kh bf16 ----------------
__global__ __launch_bounds__(256) void k_kvpost(
    const float* __restrict__ kraw, const float* __restrict__ kn_w,
    const float* __restrict__ cost, const float* __restrict__ sint,
    u16* __restrict__ kh_all)
{
  const int rid = blockIdx.x*4 + (threadIdx.x>>6);
  const int lane = threadIdx.x & 63;
  const int s = rid & 2047; int r2 = rid >> 11;
  const int kvh = r2 & 3; r2 >>= 2;
  const int b = r2 & 3; const int l = r2 >> 2;
  const float* src = kraw + ((long)(2*l)*8192 + b*2048 + s)*512 + kvh*128;
  float v0 = src[lane], v1 = src[lane+64];
  float ss = fmaf(v0,v0, v1*v1);
  #pragma unroll
  for (int msk=1; msk<64; msk<<=1) ss += __shfl_xor(ss, msk);
  float sc = rsqrtf(ss*(1.f/128.f) + 1e-6f);
  float n0 = v0*sc*kn_w[l*128+lane], n1 = v1*sc*kn_w[l*128+lane+64];
  long ti = ((long)b*2064 + s)*64 + lane;
  float co = cost[ti], si = sint[ti];
  u16* dst = kh_all + ((((long)l*4 + b)*4 + kvh)*2064 + s)*128;
  dst[lane]    = f2bf(n0*co - n1*si);
  dst[lane+64] = f2bf(n1*co + n0*si);
}

// ---------------- context V transpose -> vT bf16 (hd, s) ----------------
__global__ __launch_bounds__(256) void k_vtrans(const float* __restrict__ vraw, u16* __restrict__ vt)
{
  __shared__ float tile[32][33];
  const int st = blockIdx.x, yy = blockIdx.y, zz = blockIdx.z;
  const int hdt = yy & 3, kvh = yy >> 2;
  const int b = zz & 3, l = zz >> 2;
  const int tx = threadIdx.x & 31, ty = threadIdx.x >> 5;
  const float* src = vraw + ((long)(2*l+1)*8192 + b*2048 + st*32)*512 + kvh*128 + hdt*32;
  #pragma unroll
  for (int i=0;i<4;i++) tile[ty + i*8][tx] = src[(long)(ty + i*8)*512 + tx];
  __syncthreads();
  u16* dst = vt + ((((long)l*4 + b)*4 + kvh)*128 + hdt*32)*2064 + st*32;
  #pragma unroll
  for (int i=0;i<4;i++) dst[(long)(ty + i*8)*2064 + tx] = f2bf(tile[tx][ty + i*8]);
}

// ---------------- per-layer draft post: q/kd RMS+RoPE, vd transpose --------
__global__ __launch_bounds__(256) void k_draftpost(
    const float* __restrict__ qkv, const float* __restrict__ qn, const float* __restrict__ kn,
    const float* __restrict__ cost, const float* __restrict__ sint,
    u16* __restrict__ qf, u16* __restrict__ kh_l, u16* __restrict__ vt_l)
{
  const int rid = blockIdx.x*4 + (threadIdx.x>>6);
  const int lane = threadIdx.x & 63;
  if (rid < 1280){
    const int i = rid & 15, h = (rid>>4)%20, b = rid/320;
    const float* src = qkv + (long)(b*16+i)*3584 + h*128;
    float v0=src[lane], v1=src[lane+64];
    float ss = fmaf(v0,v0,v1*v1);
    #pragma unroll
    for (int msk=1;msk<64;msk<<=1) ss += __shfl_xor(ss, msk);
    float sc = rsqrtf(ss*(1.f/128.f) + 1e-6f);
    float n0 = v0*sc*qn[lane], n1 = v1*sc*qn[lane+64];
    long ti = ((long)b*2064 + 2048 + i)*64 + lane;
    float co = cost[ti], si = sint[ti];
    u16* dst = qf + ((long)(b*20+h)*16 + i)*128;
    dst[lane]    = f2bf(n0*co - n1*si);
    dst[lane+64] = f2bf(n1*co + n0*si);
  } else if (rid < 1536){
    const int r = rid - 1280;
    const int i = r & 15, kvh = (r>>4)&3, b = r>>6;
    const float* src = qkv + (long)(b*16+i)*3584 + 2560 + kvh*128;
    float v0=src[lane], v1=src[lane+64];
    float ss = fmaf(v0,v0,v1*v1);
    #pragma unroll
    for (int msk=1;msk<64;msk<<=1) ss += __shfl_xor(ss, msk);
    float sc = rsqrtf(ss*(1.f/128.f) + 1e-6f);
    float n0 = v0*sc*kn[lane], n1 = v1*sc*kn[lane+64];
    long ti = ((long)b*2064 + 2048 + i)*64 + lane;
    float co = cost[ti], si = sint[ti];
    u16* dst = kh_l + ((long)(b*4+kvh)*2064 + 2048 + i)*128;
    dst[lane]    = f2bf(n0*co - n1*si);
    dst[lane+64] = f2bf(n1*co + n0*si);
  } else if (rid < 1792){
    const int r = rid - 1536;
    const int i = r & 15, kvh = (r>>4)&3, b = r>>6;
    const float* src = qkv + (long)(b*16+i)*3584 + 3072 + kvh*128;
    u16* dst = vt_l + (long)(b*4+kvh)*128*2064;
    dst[(long)lane*2064 + 2048 + i]      = f2bf(src[lane]);
    dst[(long)(lane+64)*2064 + 2048 + i] = f2bf(src[lane+64]);
  }
}

// ---------------- attention: one block per (h, b); 4 waves split S ---------
__global__ __launch_bounds__(256) void k_attn(
    const u16* __restrict__ qf, const u16* __restrict__ kh, const u16* __restrict__ vt,
    u16* __restrict__ aout)
{
  __shared__ u16  pb[4][512];        // per-wave P tile 16x32 bf16
  __shared__ float osh[4][2048];     // per-wave partial O 16x128
  __shared__ float msh[4][16];
  __shared__ float lsh[4][16];
  const int h = blockIdx.x, b = blockIdx.y, kv = h/5;
  const int tid = threadIdx.x, lane = tid&63, w = tid>>6;
  const int fr = lane&15, fg = lane>>4;
  const f4v z4 = {0.f,0.f,0.f,0.f};
  s8v q[4];
  {
    const u16* qp = qf + ((long)(b*20 + h)*16 + fr)*128 + fg*8;
    #pragma unroll
    for (int kk=0;kk<4;kk++) q[kk] = *(const s8v*)(qp + kk*32);
  }
  const u16* kb_ = kh + (long)(b*4+kv)*2064*128;
  const u16* vb_ = vt + (long)(b*4+kv)*128*2064;
  f4v o[8];
  #pragma unroll
  for (int t=0;t<8;t++) o[t]=z4;
  float m_run[4], l_run[4];
  #pragma unroll
  for (int r=0;r<4;r++){ m_run[r]=-1e30f; l_run[r]=0.f; }
  const float sc = 0.08838834764831845f;   // 1/sqrt(128)
  const int niter = (w==0)?17:16;
  for (int it=0; it<niter; ++it){
    const int blk = (it<16)? (w + it*4) : 64;
    const int k0 = blk*32;
    const bool half = (blk==64);           // tail: 16 draft keys only
    f4v d0=z4, d1=z4;
    const u16* kp = kb_ + (long)(k0 + fr)*128 + fg*8;
    #pragma unroll
    for (int kk=0;kk<4;kk++){
      s8v kfr = *(const s8v*)(kp + kk*32);
      d0 = MFMA16(q[kk], kfr, d0);
    }
    if (!half){
      #pragma unroll
      for (int kk=0;kk<4;kk++){
        s8v kfr = *(const s8v*)(kp + 2048 + kk*32);
        d1 = MFMA16(q[kk], kfr, d1);
      }
    }
    float mb[4];
    #pragma unroll
    for (int r=0;r<4;r++){
      d0[r] *= sc;
      if (!half){ d1[r] *= sc; mb[r] = fmaxf(d0[r], d1[r]); }
      else mb[r] = d0[r];
    }
    #pragma unroll
    for (int msk=1; msk<16; msk<<=1){
      #pragma unroll
      for (int r=0;r<4;r++) mb[r] = fmaxf(mb[r], __shfl_xor(mb[r], msk));
    }
    float c[4];
    #pragma unroll
    for (int r=0;r<4;r++){
      float mn = fmaxf(m_run[r], mb[r]);
      c[r] = expf(m_run[r] - mn);
      float p0 = expf(d0[r] - mn);
      float p1 = half ? 0.f : expf(d1[r] - mn);
      l_run[r] = l_run[r]*c[r] + p0 + p1;
      m_run[r] = mn;
      pb[w][(fg*4+r)*32 + fr]      = f2bf(p0);
      pb[w][(fg*4+r)*32 + 16 + fr] = f2bf(p1);
    }
    #pragma unroll
    for (int t=0;t<8;t++){
      #pragma unroll
      for (int r=0;r<4;r++) o[t][r] *= c[r];
    }
    s8v pa = *(const s8v*)&pb[w][fr*32 + fg*8];
    const u16* vp = vb_ + (long)fr*2064 + k0 + (half ? (fg&1)*8 : fg*8);
    #pragma unroll
    for (int t=0;t<8;t++){
      s8v vfr = *(const s8v*)(vp + (long)t*16*2064);
      o[t] = MFMA16(pa, vfr, o[t]);
    }
  }
  #pragma unroll
  for (int msk=1; msk<16; msk<<=1){
    #pragma unroll
    for (int r=0;r<4;r++) l_run[r] += __shfl_xor(l_run[r], msk);
  }
  #pragma unroll
  for (int t=0;t<8;t++){
    #pragma unroll
    for (int r=0;r<4;r++) osh[w][(fg*4+r)*128 + t*16 + fr] = o[t][r];
  }
  if (fr==0){
    #pragma unroll
    for (int r=0;r<4;r++){ msh[w][fg*4+r]=m_run[r]; lsh[w][fg*4+r]=l_run[r]; }
  }
  __syncthreads();
  const int qi = tid>>4, hd0 = (tid&15)*8;
  float mm = fmaxf(fmaxf(msh[0][qi],msh[1][qi]), fmaxf(msh[2][qi],msh[3][qi]));
  float e0=expf(msh[0][qi]-mm), e1=expf(msh[1][qi]-mm), e2=expf(msh[2][qi]-mm), e3=expf(msh[3][qi]-mm);
  float den = lsh[0][qi]*e0 + lsh[1][qi]*e1 + lsh[2][qi]*e2 + lsh[3][qi]*e3;
  float rd = 1.f/den;
  u16* op = aout + ((long)(b*16 + qi))*2560 + h*128 + hd0;
  #pragma unroll
  for (int j=0;j<8;j++){
    float v = osh[0][qi*128+hd0+j]*e0 + osh[1][qi*128+hd0+j]*e1
            + osh[2][qi*128+hd0+j]*e2 + osh[3][qi*128+hd0+j]*e3;
    op[j] = f2bf(v*rd);
  }
}

// ---------------- silu(g)*u -> bf16 ----------------
__global__ void k_silu(const float* __restrict__ gu, u16* __restrict__ mact)
{
  const int i = blockIdx.x*256 + threadIdx.x;   // exactly 64*6912 threads
  const int m = i / 6912, n = i - m*6912;
  float g = gu[(long)m*13824 + n];
  float u = gu[(long)m*13824 + 6912 + n];
  float s = g / (1.f + expf(-g));
  mact[i] = f2bf(s*u);
}

extern "C" void kernel_launch(void* const* d_in, const int* in_sizes, int n_in,
                              void* d_out, int out_size, void* d_ws, size_t ws_size,
                              hipStream_t stream)
{
  (void)in_sizes; (void)n_in; (void)out_size; (void)ws_size;
  const float* noise  = (const float*)d_in[0];
  const float* th_in  = (const float*)d_in[1];
  const int*   pos    = (const int*)  d_in[2];
  const float* fc_w   = (const float*)d_in[3];
  const float* hnw    = (const float*)d_in[4];
  const float* q_w    = (const float*)d_in[5];
  const float* k_w    = (const float*)d_in[6];
  const float* v_w    = (const float*)d_in[7];
  const float* o_w    = (const float*)d_in[8];
  const float* qn_w   = (const float*)d_in[9];
  const float* kn_w   = (const float*)d_in[10];
  const float* gate_w = (const float*)d_in[11];
  const float* up_w   = (const float*)d_in[12];
  const float* down_w = (const float*)d_in[13];
  const float* ln1_w  = (const float*)d_in[14];
  const float* ln2_w  = (const float*)d_in[15];
  const float* norm_w = (const float*)d_in[16];
  float* out = (float*)d_out;
  char* ws = (char*)d_ws;

  // workspace layout (total ~438.5 MB, with lifetime-based aliasing)
  u16*   th_bfin = (u16*)(ws);                 // 209,715,200 B (dead after fc gemm)
  float* kcvc    = (float*)(ws);               // alias: 167,772,160 B
  u16*   fcw_bf  = (u16*)(ws + 209715200L);    // 65,536,000 B (dead after fc gemm)
  u16*   kh_all  = (u16*)(ws + 209715200L);    // alias: 42,270,720 B
  u16*   kvw_bf  = (u16*)(ws + 275251200L);    // 26,214,400 B
  float* cost    = (float*)(ws + 301465600L);  // 2,113,536 B
  float* sint    = (float*)(ws + 303579136L);  // 2,113,536 B
  float* th_raw  = (float*)(ws + 305692672L);  // 83,886,080 B (dead after th rms)
  u16*   vt_all  = (u16*)(ws + 305692672L);    // alias: 42,270,720 B
  u16*   th_bf   = (u16*)(ws + 389578752L);    // 41,943,040 B
  float* x       = (float*)(ws + 431521792L);  // 655,360 B
  u16*   hn      = (u16*)(ws + 432177152L);    // 327,680 B
  float* qkvraw  = (float*)(ws + 432504832L);  // 917,504 B
  u16*   qf      = (u16*)(ws + 433422336L);    // 327,680 B
  u16*   aout    = (u16*)(ws + 433750016L);    // 327,680 B
  float* guraw   = (float*)(ws + 434077696L);  // 3,538,944 B
  u16*   mact    = (u16*)(ws + 437616640L);    // 884,736 B

  hipMemcpyAsync(x, noise, 64L*2560*4, hipMemcpyDeviceToDevice, stream);
  k_prep<<<2048,256,0,stream>>>(th_in, fc_w, k_w, v_w, pos, th_bfin, fcw_bf, kvw_bf, cost, sint);
  // th = target_hidden @ fc_w^T  (M=8192,N=2560,K=12800)
  k_gemm_bt<<<dim3(20,64,1),256,0,stream>>>(th_bfin, fcw_bf, th_raw, 8192, 2560, 12800, 0, 0);
  k_rms_row<<<8192,256,0,stream>>>(th_raw, hnw, th_bf, (float*)0, 2560);
  // kc/vc for all 5 layers: z = 2*l + (0:k,1:v)
  k_gemm_bt<<<dim3(4,64,10),256,0,stream>>>(th_bf, kvw_bf, kcvc, 8192, 512, 2560, 1310720L, 4194304L);
  k_kvpost<<<40960,256,0,stream>>>(kcvc, kn_w, cost, sint, kh_all);
  k_vtrans<<<dim3(64,16,20),256,0,stream>>>(kcvc, vt_all);

  for (int l=0;l<5;l++){
    u16* kh_l = kh_all + (long)l*4*4*2064*128;
    u16* vt_l = vt_all + (long)l*4*4*2064*128;
    k_rms_row<<<64,256,0,stream>>>(x, ln1_w + l*2560, hn, (float*)0, 2560);
    hipMemsetAsync(qkvraw, 0, 917504L, stream);
    k_skinny<<<dim3(40,5),256,0,stream>>>(hn, q_w + (long)l*6553600, qkvraw, 2560, 3584, 0,    512);
    k_skinny<<<dim3(8,5),256,0,stream>>>(hn, k_w + (long)l*1310720, qkvraw, 2560, 3584, 2560, 512);
    k_skinny<<<dim3(8,5),256,0,stream>>>(hn, v_w + (long)l*1310720, qkvraw, 2560, 3584, 3072, 512);
    k_draftpost<<<448,256,0,stream>>>(qkvraw, qn_w + l*128, kn_w + l*128, cost, sint, qf, kh_l, vt_l);
    k_attn<<<dim3(20,4),256,0,stream>>>(qf, kh_l, vt_l, aout);
    k_skinny<<<dim3(40,5),256,0,stream>>>(aout, o_w + (long)l*6553600, x, 2560, 2560, 0, 512); // x += out@o^T
    k_rms_row<<<64,256,0,stream>>>(x, ln2_w + l*2560, hn, (float*)0, 2560);
    hipMemsetAsync(guraw, 0, 3538944L, stream);
    k_skinny<<<dim3(108,5),256,0,stream>>>(hn, gate_w + (long)l*17694720, guraw, 2560, 13824, 0,    512);
    k_skinny<<<dim3(108,5),256,0,stream>>>(hn, up_w   + (long)l*17694720, guraw, 2560, 13824, 6912, 512);
    k_silu<<<1728,256,0,stream>>>(guraw, mact);
    k_skinny<<<dim3(40,12),256,0,stream>>>(mact, down_w + (long)l*17694720, x, 6912, 2560, 0, 576); // x += ...
  }
  k_rms_row<<<64,256,0,stream>>>(x, norm_w, (u16*)0, out, 2560);
}